// Round 13
// baseline (500.807 us; speedup 1.0000x reference)
//
#include <hip/hip_runtime.h>

// Palettized 3x3 VALID conv as implicit GEMM:
//   C[M=16*254*254, 64] = A[M, K=576] * B[K=576, 64],  K = (kh*3+kw)*64 + c
// Round-13: FULL-ROW PAGE-DENSE TILE. R12 (+8%, only win in 12 rounds)
// validated the DRAM-page model: BW tracks bytes/activate. Finish the axis:
// block = 2oh x 254ow(full) x 64O, 512 thr. Staging reads whole 1024B x-rows
// (100% page use, zero tail code); stores stay 512B f32x2 runs. Wave shape =
// R12's exactly (1oh x 128ow x 32O, acc[8][2], a:MFMA = 1:2). Channel-split
// 2-phase; LDS 4cblk x 4rows x 258-pitch (+pad) = 66176B -> 2 blocks/CU =
// 16 waves/CU (same as R12 -> page density isolated). mt-edge A-reads hit
// the 2-granule garbage pad; their products only reach masked ow>=254.

typedef __bf16 bf16x8 __attribute__((ext_vector_type(8)));
typedef float f32x4 __attribute__((ext_vector_type(4)));
typedef float f32x2 __attribute__((ext_vector_type(2)));

union Frag {
    uint4 q;
    bf16x8 v;
};

// ---- B dequant/swizzle: Bws[s]  s = (kc*4 + nt)*64 + lane, 16B per slot.
// lane holds B[k = kc*32 + (lane>>4)*8 + j][o = nt*16 + (lane&15)], j=0..7
// with k = (kh*3+kw)*64 + c  ->  kc: r = kc>>1 fixed, c = (kc&1)*32 + (lane>>4)*8 + j.
__global__ __launch_bounds__(256) void dequant_B(
        const float* __restrict__ lut, const int* __restrict__ widx,
        uint4* __restrict__ Bws) {
    int s = blockIdx.x * 256 + threadIdx.x;   // 0..4607
    int l = s & 63;
    int nt = (s >> 6) & 3;
    int kc = s >> 8;
    if (kc >= 18) return;
    int r = kc >> 1;
    int kh = r / 3, kw = r - kh * 3;
    int o = nt * 16 + (l & 15);
    int c0 = (kc & 1) * 32 + (l >> 4) * 8;
    Frag f;
#pragma unroll
    for (int j = 0; j < 8; ++j) {
        int c = c0 + j;
        int idx = widx[((o * 64 + c) * 3 + kh) * 3 + kw];
        f.v[j] = (__bf16)lut[idx];
    }
    Bws[s] = f.q;
}

// LDS granule layout: gidx = cbl*A_CBL + row*A_ROW + col, 16B granules.
// cols 0..255 written (full x row); 256..257 garbage pad (read-only, masked).
// A_ROW=258 (4128B = 32 mod 128 -> rows offset 8 banks); A_CBL=1034
// (16544B = 32 mod 128 -> l4 groups offset 8 banks). Total 4136 granules.
#define A_ROW 258
#define A_CBL 1034

__global__ __launch_bounds__(512, 4) void conv_mfma(
        const float* __restrict__ x, const float* __restrict__ bias,
        const uint4* __restrict__ Bws, float* __restrict__ out) {
    __shared__ uint4 ldsA[4136];          // 66176 B -> 2 blocks/CU
    unsigned* lds32 = (unsigned*)ldsA;

    int bx = blockIdx.x;                  // natural order (ohp-adjacent close)
    int ohp = bx % 127;                   // 0..126
    int n   = bx / 127;                   // 0..15
    int oh0 = ohp * 2;                    // 0..252 (rows oh0, oh0+1)
    int t = threadIdx.x;

    const float* xn = x + (size_t)n * (64 * 256 * 256);

    int w = t >> 6;                       // wave 0..7
    int l = t & 63;
    int l15 = l & 15, l4 = l >> 4;

    // staging roles: wave w -> cblk (w&3), row-pair (w>>2); lane = (chp=l4, colg=l15)
    int st_cbl = w & 3;
    int st_rp  = w >> 2;                  // 0..1
    // compute roles
    int ohl = (w >> 2) & 1;               // oh row in tile
    int owh = (w >> 1) & 1;               // ow half (0:cols 0-127, 1:128-255)
    int og  = w & 1;                      // O half (32 planes)

    f32x4 acc[8][2] = {};

    for (int h = 0; h < 2; ++h) {
        // ---- stage x[n, h*32:(h+1)*32, oh0:oh0+4, 0:256] -> LDS (full rows)
        {
            const float* cb = xn
                + (size_t)((h * 4 + st_cbl) * 8 + l4 * 2) * 65536 + l15 * 4;
#pragma unroll
            for (int rr = 0; rr < 2; ++rr) {
                int row = st_rp * 2 + rr;
                const float* pr = cb + (oh0 + row) * 256;
                f32x4 f0[4], f1[4];
#pragma unroll
                for (int cb2 = 0; cb2 < 4; ++cb2) {
                    f0[cb2] = *(const f32x4*)(pr + cb2 * 64);
                    f1[cb2] = *(const f32x4*)(pr + cb2 * 64 + 65536);
                }
#pragma unroll
                for (int cb2 = 0; cb2 < 4; ++cb2) {
                    int gbase = st_cbl * A_CBL + row * A_ROW + cb2 * 64 + l15 * 4;
#pragma unroll
                    for (int i = 0; i < 4; ++i) {
                        union { __bf16 hh[2]; unsigned u; } bp;
                        bp.hh[0] = (__bf16)f0[cb2][i];
                        bp.hh[1] = (__bf16)f1[cb2][i];
                        lds32[(gbase + i) * 4 + l4] = bp.u;
                    }
                }
            }
        }
        __syncthreads();

        // ---- 9 kc chunks of parity h: kc = 2*i + h (r = i).
        // A granule cbl=l4 of phase h holds channels h*32 + l4*8 + j == B's c.
#pragma unroll
        for (int i = 0; i < 9; ++i) {
            int kh = i / 3, kw = i - kh * 3;     // compile-time
            int kc = 2 * i + h;

            Frag b[2];
#pragma unroll
            for (int nt = 0; nt < 2; ++nt)
                b[nt].q = Bws[(kc * 4 + og * 2 + nt) * 64 + l];

            Frag a[8];
#pragma unroll
            for (int mt = 0; mt < 8; ++mt)
                a[mt].q = ldsA[l4 * A_CBL + (ohl + kh) * A_ROW
                               + owh * 128 + mt * 16 + l15 + kw];

#pragma unroll
            for (int mt = 0; mt < 8; ++mt)
#pragma unroll
                for (int nt = 0; nt < 2; ++nt)
                    acc[mt][nt] = __builtin_amdgcn_mfma_f32_16x16x32_bf16(
                        a[mt].v, b[nt].v, acc[mt][nt], 0, 0, 0);
        }
        __syncthreads();   // h=0: protect before restage; h=1: before slab
    }

    // ---- epilogue: per-wave slab transpose -> f32x2 stores (512B runs).
    // acc C/D: lane l holds out[o=og*32+nt*16+l15][oh0+ohl][owh*128+mt*16+l4*4+rg].
    float* slab = (float*)ldsA + w * 2064;       // 16 x 129 f32 per wave
    int oh = oh0 + ohl;                          // always <= 253
#pragma unroll
    for (int nt = 0; nt < 2; ++nt) {
        // scatter: 16 o-rows (l15) x 128 cols, pitch 129
#pragma unroll
        for (int mt = 0; mt < 8; ++mt)
#pragma unroll
            for (int rg = 0; rg < 4; ++rg)
                slab[l15 * 129 + mt * 16 + l4 * 4 + rg] = acc[mt][nt][rg];
        // gather transposed: lane l -> cols owh*128 + 2l, 2l+1
#pragma unroll
        for (int j = 0; j < 16; ++j) {
            int o = og * 32 + nt * 16 + j;
            float bv = bias[o];
            f32x2 v;
            v[0] = slab[j * 129 + 2 * l] + bv;
            v[1] = slab[j * 129 + 2 * l + 1] + bv;
            int col = owh * 128 + 2 * l;
            if (col + 1 < 254)               // masks only owh=1, l=63
                *(f32x2*)(out + (((size_t)n * 64 + o) * 254 + oh) * 254 + col) = v;
        }
    }
}

extern "C" void kernel_launch(void* const* d_in, const int* in_sizes, int n_in,
                              void* d_out, int out_size, void* d_ws, size_t ws_size,
                              hipStream_t stream) {
    const float* x    = (const float*)d_in[0];
    const float* lut  = (const float*)d_in[1];
    const int*   widx = (const int*)d_in[2];
    const float* bias = (const float*)d_in[3];
    float* out = (float*)d_out;
    uint4* Bws = (uint4*)d_ws;   // needs 73728 B

    dequant_B<<<18, 256, 0, stream>>>(lut, widx, Bws);
    conv_mfma<<<16 * 127, 512, 0, stream>>>(x, bias, (const uint4*)Bws, out);
}

// Round 14
// 486.804 us; speedup vs baseline: 1.0288x; 1.0288x over previous
//
#include <hip/hip_runtime.h>

// Palettized 3x3 VALID conv as implicit GEMM:
//   C[M=16*254*254, 64] = A[M, K=576] * B[K=576, 64],  K = (kh*3+kw)*64 + c
// Round-14: R12 (180us best) + TRUE ASYNC A-PREFETCH. Mechanism: compute
// phases have zero HBM demand -> BW duty-cycle limited to ~3.2 of the
// demonstrated 4.07 TB/s (R9, 8 waves/CU). Prior overlap attempts failed
// for fixable reasons: R1/R9 reg-spill; R10's in-loop global B-loads force
// vmcnt waits that drain the OLDER A-prefetch (vmcnt is oldest-first).
// Fix: preload the phase's 18 B-fragments into regs BEFORE the kc loop ->
// compute loop has NO VMEM -> A-prefetch (issued pre-loop) stays in flight
// across all 9 kc. Raw lgkm-only barriers (R1-proven) avoid the compiler's
// vmcnt(0)-before-s_barrier drain. Budget at 2 blocks/CU (cap 256): acc 64
// + breg 72 + prefetch 64+8 + working ~ 230. Tile/staging/epilogue = R12.

typedef __bf16 bf16x8 __attribute__((ext_vector_type(8)));
typedef float f32x4 __attribute__((ext_vector_type(4)));
typedef float f32x2 __attribute__((ext_vector_type(2)));

union Frag {
    uint4 q;
    bf16x8 v;
};

#define LGKM_BARRIER() do { \
    asm volatile("s_waitcnt lgkmcnt(0)" ::: "memory"); \
    __builtin_amdgcn_s_barrier(); \
    asm volatile("" ::: "memory"); } while (0)

// ---- B dequant/swizzle: Bws[s]  s = (kc*4 + nt)*64 + lane, 16B per slot.
// lane holds B[k = kc*32 + (lane>>4)*8 + j][o = nt*16 + (lane&15)], j=0..7
// with k = (kh*3+kw)*64 + c  ->  kc: r = kc>>1 fixed, c = (kc&1)*32 + (lane>>4)*8 + j.
__global__ __launch_bounds__(256) void dequant_B(
        const float* __restrict__ lut, const int* __restrict__ widx,
        uint4* __restrict__ Bws) {
    int s = blockIdx.x * 256 + threadIdx.x;   // 0..4607
    int l = s & 63;
    int nt = (s >> 6) & 3;
    int kc = s >> 8;
    if (kc >= 18) return;
    int r = kc >> 1;
    int kh = r / 3, kw = r - kh * 3;
    int o = nt * 16 + (l & 15);
    int c0 = (kc & 1) * 32 + (l >> 4) * 8;
    Frag f;
#pragma unroll
    for (int j = 0; j < 8; ++j) {
        int c = c0 + j;
        int idx = widx[((o * 64 + c) * 3 + kh) * 3 + kw];
        f.v[j] = (__bf16)lut[idx];
    }
    Bws[s] = f.q;
}

// LDS: ldsA[cbl][pix] 16B granules; pix = row*132 + col (rows 0..3, cols 0..129,
// pitch 132). cbl stride A_CB=530 granules. granule = 8 bf16 channels,
// u32 word chp = packed (ch 2*chp, 2*chp+1).  (R12 layout, verified.)
#define A_CB 530

__global__ __launch_bounds__(256, 2) void conv_mfma(
        const float* __restrict__ x, const float* __restrict__ bias,
        const uint4* __restrict__ Bws, float* __restrict__ out) {
    __shared__ uint4 ldsA[4 * A_CB];      // 33920 B
    unsigned* lds32 = (unsigned*)ldsA;

    int bx = blockIdx.x;                  // natural order
    int owt = bx & 1;
    int rem = bx >> 1;
    int ohp = rem % 127;                  // 0..126
    int n   = rem / 127;                  // 0..15
    int ow0 = owt * 128;                  // 0,128
    int oh0 = ohp * 2;                    // 0..252
    int t = threadIdx.x;

    const float* xn = x + (size_t)n * (64 * 256 * 256);

    int w = t >> 6;                       // wave 0..3
    int l = t & 63;
    int l15 = l & 15, l4 = l >> 4;

    // tail staging (cols 128,129): 4 cbl x 4 row x 2 col = 32 granules, t<32
    int tl_cb  = t & 3;
    int tl_rc  = t >> 2;                  // 0..7 for t<32
    int tl_rr  = tl_rc >> 1;              // 0..3
    int tl_col = 128 + (tl_rc & 1);
    int tl_xc  = ow0 + tl_col; if (tl_xc > 255) tl_xc = 255;

    int ohl = w >> 1;                     // wave's oh row in tile (0..1)
    int ob  = (w & 1) * 2;                // wave's B nt-offset (O-half)

    f32x4 acc[8][2] = {};
    uint4 breg[18];                       // whole phase's B (this wave's O-half)
    f32x4 pf0[8], pf1[8];                 // A-prefetch (16 dwordx4)
    float tpre[8];                        // tail prefetch (wave 0, lanes<32)

    auto loadB = [&](int h) {
#pragma unroll
        for (int i = 0; i < 9; ++i) {
            int kc = 2 * i + h;
            breg[i * 2 + 0] = Bws[(kc * 4 + ob + 0) * 64 + l];
            breg[i * 2 + 1] = Bws[(kc * 4 + ob + 1) * 64 + l];
        }
    };

    // issue the 16 (+8 tail) global loads of phase h's A-half
    auto prefA = [&](int h) {
        const float* cbase = xn + (size_t)((h * 4 + w) * 8 + l4 * 2) * 65536 + ow0;
#pragma unroll
        for (int ch2 = 0; ch2 < 2; ++ch2) {
            const float* pb = cbase + ch2 * 64 + l15 * 4;
#pragma unroll
            for (int rr = 0; rr < 4; ++rr) {
                const float* p = pb + (oh0 + rr) * 256;
                pf0[ch2 * 4 + rr] = *(const f32x4*)(p);
                pf1[ch2 * 4 + rr] = *(const f32x4*)(p + 65536);
            }
        }
        if (t < 32) {
            const float* src = xn + (size_t)((h * 4 + tl_cb) * 8) * 65536
                               + (oh0 + tl_rr) * 256 + tl_xc;
#pragma unroll
            for (int j = 0; j < 8; ++j)
                tpre[j] = src[j * 65536];
        }
    };

    // convert + scatter the prefetched A into LDS (vmcnt waits land here)
    auto writeA = [&]() {
#pragma unroll
        for (int ch2 = 0; ch2 < 2; ++ch2)
#pragma unroll
            for (int rr = 0; rr < 4; ++rr) {
                int gbase = w * A_CB + rr * 132 + ch2 * 64 + l15 * 4;
#pragma unroll
                for (int i = 0; i < 4; ++i) {
                    union { __bf16 hh[2]; unsigned u; } bp;
                    bp.hh[0] = (__bf16)pf0[ch2 * 4 + rr][i];
                    bp.hh[1] = (__bf16)pf1[ch2 * 4 + rr][i];
                    lds32[(gbase + i) * 4 + l4] = bp.u;
                }
            }
        if (t < 32) {
            Frag f;
#pragma unroll
            for (int j = 0; j < 8; ++j)
                f.v[j] = (__bf16)tpre[j];
            ldsA[tl_cb * A_CB + tl_rr * 132 + tl_col] = f.q;
        }
    };

    // 9 kc of one parity; B from regs, A from LDS -> NO VMEM inside
    auto compute = [&]() {
#pragma unroll
        for (int i = 0; i < 9; ++i) {
            int kh = i / 3, kw = i - kh * 3;       // compile-time
            Frag b0, b1;
            b0.q = breg[i * 2 + 0];
            b1.q = breg[i * 2 + 1];
            Frag a[8];
#pragma unroll
            for (int mt = 0; mt < 8; ++mt)
                a[mt].q = ldsA[l4 * A_CB + (ohl + kh) * 132 + l15 + kw + mt * 16];
#pragma unroll
            for (int mt = 0; mt < 8; ++mt) {
                acc[mt][0] = __builtin_amdgcn_mfma_f32_16x16x32_bf16(
                    a[mt].v, b0.v, acc[mt][0], 0, 0, 0);
                acc[mt][1] = __builtin_amdgcn_mfma_f32_16x16x32_bf16(
                    a[mt].v, b1.v, acc[mt][1], 0, 0, 0);
            }
        }
    };

    // ---- pipeline ----
    loadB(0);                  // 18 B-loads (L2 after first blocks)
    prefA(0);                  // 16+8 A-loads, deep MLP at prologue
    writeA();                  // waits loads; stage h0 into LDS
    LGKM_BARRIER();            // h0 visible
    prefA(1);                  // issue h1's A-loads -- stay in flight
    asm volatile("" ::: "memory");   // pin issue before the loop
    compute();                 // h0: zero VMEM -> prefetch survives
    loadB(1);                  // B for h1 (WAR on breg after last use)
    LGKM_BARRIER();            // raw: no vmcnt drain; LDS reads done
    writeA();                  // h1 latency already paid under compute
    LGKM_BARRIER();
    compute();                 // h1
    LGKM_BARRIER();            // before slab reuse

    // ---- epilogue: slab transpose -> f32x2 stores (512B runs). R12 verbatim.
    // acc C/D: lane l holds out[o=oseg+nt*16+l15][oh0+ohl][ow0+mt*16+l4*4+rg].
    float* slab = (float*)ldsA + w * (16 * 130);   // 8320 B per wave
    int oseg = (w & 1) * 32;
    int oh = oh0 + ohl;                            // always < 254
    float* orow = out + ((size_t)n * 64 * 254 + oh) * 254 + ow0;
    bool ok = (ow0 + l * 2 + 1) < 254;
#pragma unroll
    for (int nt = 0; nt < 2; ++nt) {
#pragma unroll
        for (int mt = 0; mt < 8; ++mt)
#pragma unroll
            for (int rg = 0; rg < 4; ++rg)
                slab[l15 * 130 + mt * 16 + l4 * 4 + rg] = acc[mt][nt][rg];
#pragma unroll
        for (int j = 0; j < 16; ++j) {
            int o = oseg + nt * 16 + j;
            float bv = bias[o];
            f32x2 v;
            v[0] = slab[j * 130 + l * 2]     + bv;
            v[1] = slab[j * 130 + l * 2 + 1] + bv;
            if (ok)
                *(f32x2*)(orow + (size_t)o * (254 * 254) + l * 2) = v;
        }
    }
}

extern "C" void kernel_launch(void* const* d_in, const int* in_sizes, int n_in,
                              void* d_out, int out_size, void* d_ws, size_t ws_size,
                              hipStream_t stream) {
    const float* x    = (const float*)d_in[0];
    const float* lut  = (const float*)d_in[1];
    const int*   widx = (const int*)d_in[2];
    const float* bias = (const float*)d_in[3];
    float* out = (float*)d_out;
    uint4* Bws = (uint4*)d_ws;   // needs 73728 B

    dequant_B<<<18, 256, 0, stream>>>(lut, widx, Bws);
    conv_mfma<<<16 * 127 * 2, 256, 0, stream>>>(x, bias, (const uint4*)Bws, out);
}